// Round 16
// baseline (129.321 us; speedup 1.0000x reference)
//
#include <hip/hip_runtime.h>
#include <hip/hip_bf16.h>

#define B_TOT   4096
#define T_STEPS 256
#define IN_D    28
#define HID     128
#define OUT_D   784
#define BM      8

typedef __bf16 bf16x8 __attribute__((ext_vector_type(8)));
typedef __bf16 bf16x4 __attribute__((ext_vector_type(4)));
typedef float  f32x4  __attribute__((ext_vector_type(4)));
typedef float  f32x2  __attribute__((ext_vector_type(2)));

__device__ __forceinline__ float bf2f(__bf16 b) {
    unsigned short s = __builtin_bit_cast(unsigned short, b);
    unsigned int u = ((unsigned int)s) << 16;
    return __builtin_bit_cast(float, u);
}
__device__ __forceinline__ unsigned short f2bfbits(float f) {
    unsigned int u = __builtin_bit_cast(unsigned int, f);
    u += 0x7fffu + ((u >> 16) & 1u);   // RNE (finite values)
    return (unsigned short)(u >> 16);
}

// Swizzled row layout (verified r7..r15): row stride 256B, byte ^= (row&7)<<4.
__device__ __forceinline__ int hswz(int row, int byteInRow) {
    return row * 256 + (byteInRow ^ ((row & 7) << 4));
}

// Loop barrier: drains LDS only (verified win r15). In-flight x loads survive.
#define BARLDS() asm volatile("s_waitcnt lgkmcnt(0)\n\ts_barrier" ::: "memory")

// r16: BM=8, 512 blocks -> TWO blocks per CU with INDEPENDENT barriers.
// 16 waves/CU (4/SIMD) from two decorrelated schedules: block A's barrier
// stall is filled by block B's LDS reads + MFMAs. MFMA N-dim half wasted
// (cols 8-15 = broadcast duplicates, reads row ln15&7 -> same-address
// broadcast = free), h-writes exec-masked to ln15<8.
__global__ __launch_bounds__(512) void rnn_fused(
    const float* __restrict__ x,     // [B,T,IN] f32
    const float* __restrict__ h0,    // [B,HID] f32
    const float* __restrict__ W_ih,  // [HID,IN] f32
    const float* __restrict__ b_ih,  // [HID] f32
    const float* __restrict__ W_hh,  // [HID,HID] f32
    const float* __restrict__ b_hh,  // [HID] f32
    const float* __restrict__ W_ho,  // [OUT_D,HID] f32
    const float* __restrict__ b_ho,  // [OUT_D] f32
    float* __restrict__ out)         // [B*OUT_D] f32, then [B*HID] f32
{
    __shared__ __align__(16) unsigned char Hb[2][BM * 256]; // h (bf16) double buffer
    __shared__ __align__(16) unsigned char Xs[8 * BM * 256];// x ring: 8 swizzled slots

    const int tid  = threadIdx.x;
    const int lane = tid & 63;
    const int wv   = tid >> 6;       // wave 0..7
    const int ln15 = lane & 15;
    const int ln7  = lane & 7;       // batch row (broadcast pairs ln15, ln15+8)
    const int lg   = lane >> 4;      // k-group 0..3
    const int b0   = blockIdx.x * BM;

    // ---- Weight fragments (f32 -> bf16), register-resident, MFMA *A* operand:
    // A[m = n_out][k], lane: m = nt0 + ln15, k = 8*lg + e.  (verified r7)
    const int nt0 = wv * 16;         // this wave owns hidden cols [nt0, nt0+16)
    bf16x8 bw[4];
    #pragma unroll
    for (int kc = 0; kc < 4; ++kc) {
        const float* p = W_hh + (nt0 + ln15) * HID + kc * 32 + lg * 8;
        bf16x8 v;
        #pragma unroll
        for (int e = 0; e < 8; ++e) v[e] = (__bf16)p[e];
        bw[kc] = v;
    }
    const __bf16 bzero = (__bf16)0.0f;
    bf16x8 bxf;
    {
        int n = nt0 + ln15;
        #pragma unroll
        for (int e = 0; e < 8; ++e) {
            int k = lg * 8 + e;
            bxf[e] = (k < IN_D) ? (__bf16)W_ih[n * IN_D + k] : bzero;  // zero-pad K 28->32
        }
    }
    // bias per lane: D row = n_out = nt0 + 4*lg + r  (4 consecutive)
    f32x4 bias4;
    {
        int n = nt0 + 4 * lg;
        f32x4 bi = *(const f32x4*)(b_ih + n);
        f32x4 bh = *(const f32x4*)(b_hh + n);
        bias4 = bi + bh;
    }

    // ---- stage initial hidden into Hb[0] (f32 -> bf16): 8 rows x 16 cg
    if (tid < 128) {
        int row = tid >> 4, cg = tid & 15;
        const float* p = h0 + (size_t)(b0 + row) * HID + cg * 8;
        bf16x8 hv;
        #pragma unroll
        for (int e = 0; e < 8; ++e) hv[e] = (__bf16)p[e];
        *(bf16x8*)(&Hb[0][hswz(row, cg * 16)]) = hv;
    }
    // ---- zero the k=28..31 pad (bytes 56..63 of each row) of all 8 ring slots
    if (tid < 128) {
        int slot = tid >> 4, idx = tid & 15, row = idx >> 1, d = idx & 1;
        *(unsigned int*)(&Xs[slot * (BM * 256) + hswz(row, 56 + d * 4)]) = 0u;
    }
    // ---- x staging geometry: 112 threads, 8 rows x 14 dword-pairs
    const int xrow = (tid / 14) & 7, xpair = tid % 14;
    const bool xthr = (tid < 112);
    const float* xbase = x + (size_t)(b0 + xrow) * T_STEPS * IN_D + xpair * 2;
    // ---- pre-stage steps 0..3 into slots 0..3
    if (xthr) {
        #pragma unroll
        for (int s = 0; s < 4; ++s) {
            f32x2 v = *(const f32x2*)(xbase + (size_t)s * IN_D);
            unsigned int pk = ((unsigned int)f2bfbits(v[1]) << 16) | f2bfbits(v[0]);
            *(unsigned int*)(&Xs[s * (BM * 256) + hswz(xrow, xpair * 4)]) = pk;
        }
    }
    f32x2 sx0 = {0.f, 0.f}, sx1 = sx0, sx2 = sx0, sx3 = sx0;
    __syncthreads();

    // ================= recurrence: 256 steps, 1 raw barrier/step =============
    // Consume path (verified r7..r15), re-rowed to ln7 (broadcast): lane holds
    // batch=ln15 (cols 8-15 duplicate 0-7), n_out = nt0+4lg+r. Staging
    // pipeline (verified r15): load at T, pack+write at T+2, first read T+4.
#define STEP(T, STGL, STGW)                                                     \
    {                                                                           \
        const int rb = (T) & 1;                                                 \
        STGL                                                                    \
        bf16x8 ax  = *(const bf16x8*)(&Xs[((T) & 7) * (BM * 256) + hswz(ln7, lg * 16)]); \
        bf16x8 ah0 = *(const bf16x8*)(&Hb[rb][hswz(ln7,   0 + lg * 16)]);       \
        bf16x8 ah1 = *(const bf16x8*)(&Hb[rb][hswz(ln7,  64 + lg * 16)]);       \
        bf16x8 ah2 = *(const bf16x8*)(&Hb[rb][hswz(ln7, 128 + lg * 16)]);       \
        bf16x8 ah3 = *(const bf16x8*)(&Hb[rb][hswz(ln7, 192 + lg * 16)]);       \
        f32x4 zz = {0.f, 0.f, 0.f, 0.f};                                        \
        f32x4 a = __builtin_amdgcn_mfma_f32_16x16x32_bf16(bxf,   ax,  bias4, 0, 0, 0); \
        f32x4 c = __builtin_amdgcn_mfma_f32_16x16x32_bf16(bw[1], ah1, zz, 0, 0, 0); \
        a = __builtin_amdgcn_mfma_f32_16x16x32_bf16(bw[0], ah0, a, 0, 0, 0);    \
        c = __builtin_amdgcn_mfma_f32_16x16x32_bf16(bw[3], ah3, c, 0, 0, 0);    \
        a = __builtin_amdgcn_mfma_f32_16x16x32_bf16(bw[2], ah2, a, 0, 0, 0);    \
        f32x4 s = a + c;                                                        \
        bf16x4 w;                                                               \
        _Pragma("unroll")                                                       \
        for (int r = 0; r < 4; ++r) {                                           \
            float v = s[r];                                                     \
            w[r] = (__bf16)(v > 0.f ? v : 0.f);                                 \
        }                                                                       \
        if (ln15 < 8)                                                           \
            *(bf16x4*)(&Hb[rb ^ 1][hswz(ln15, nt0 * 2 + lg * 8)]) = w;          \
        STGW                                                                    \
        BARLDS();                                                               \
    }

#define STG_LOAD(T)                                                             \
        if (((T) + 4 < T_STEPS) && xthr) {                                      \
            sx0 = *(const f32x2*)(xbase + (size_t)((T) + 4) * IN_D);            \
            sx1 = *(const f32x2*)(xbase + (size_t)((T) + 5) * IN_D);            \
            sx2 = *(const f32x2*)(xbase + (size_t)((T) + 6) * IN_D);            \
            sx3 = *(const f32x2*)(xbase + (size_t)((T) + 7) * IN_D);            \
        }
#define STG_WRITE(T)                                                            \
        if (((T) + 4 < T_STEPS) && xthr) {                                      \
            unsigned int p0 = ((unsigned int)f2bfbits(sx0[1]) << 16) | f2bfbits(sx0[0]); \
            unsigned int p1 = ((unsigned int)f2bfbits(sx1[1]) << 16) | f2bfbits(sx1[0]); \
            unsigned int p2 = ((unsigned int)f2bfbits(sx2[1]) << 16) | f2bfbits(sx2[0]); \
            unsigned int p3 = ((unsigned int)f2bfbits(sx3[1]) << 16) | f2bfbits(sx3[0]); \
            *(unsigned int*)(&Xs[(((T) + 4) & 7) * (BM * 256) + hswz(xrow, xpair * 4)]) = p0; \
            *(unsigned int*)(&Xs[(((T) + 5) & 7) * (BM * 256) + hswz(xrow, xpair * 4)]) = p1; \
            *(unsigned int*)(&Xs[(((T) + 6) & 7) * (BM * 256) + hswz(xrow, xpair * 4)]) = p2; \
            *(unsigned int*)(&Xs[(((T) + 7) & 7) * (BM * 256) + hswz(xrow, xpair * 4)]) = p3; \
        }

    for (int t = 0; t < T_STEPS; t += 8) {
        STEP(t + 0, STG_LOAD(t + 0), )
        STEP(t + 1, , )
        STEP(t + 2, , STG_WRITE(t + 0))
        STEP(t + 3, , )
        STEP(t + 4, STG_LOAD(t + 4), )
        STEP(t + 5, , )
        STEP(t + 6, , STG_WRITE(t + 4))
        STEP(t + 7, , )
    }
#undef STEP
#undef STG_LOAD
#undef STG_WRITE
    // after t=255 (rb=1) the final h sits in Hb[0]; loop's last BARLDS done

    // ================= epilogue (verified r7, BM=8 masked) =================
    // h_final -> d_out second segment (f32)
    if (tid < 128) {
        int row = tid >> 4, cg = tid & 15;
        bf16x8 hv = *(const bf16x8*)(&Hb[0][hswz(row, cg * 16)]);
        float* po = out + (size_t)B_TOT * OUT_D + (size_t)(b0 + row) * HID + cg * 8;
        #pragma unroll
        for (int e = 0; e < 8; ++e) po[e] = bf2f(hv[e]);
    }
    // projection (transposed form): D[o][batch], A = W_ho frag, B = h frag.
    bf16x8 af[4];
    #pragma unroll
    for (int kc = 0; kc < 4; ++kc)
        af[kc] = *(const bf16x8*)(&Hb[0][hswz(ln7, kc * 64 + lg * 16)]);

    for (int nt = wv; nt < 49; nt += 8) {
        f32x4 acc = *(const f32x4*)(b_ho + nt * 16 + 4 * lg);
        #pragma unroll
        for (int kc = 0; kc < 4; ++kc) {
            const float* p = W_ho + (nt * 16 + ln15) * HID + kc * 32 + lg * 8;
            bf16x8 bfrag;
            #pragma unroll
            for (int e = 0; e < 8; ++e) bfrag[e] = (__bf16)p[e];
            acc = __builtin_amdgcn_mfma_f32_16x16x32_bf16(bfrag, af[kc], acc, 0, 0, 0);
        }
        // lane holds batch=ln15 (valid <8), o = nt*16 + 4lg + r
        if (ln15 < 8)
            *(f32x4*)(out + (size_t)(b0 + ln15) * OUT_D + nt * 16 + 4 * lg) = acc;
    }
}

extern "C" void kernel_launch(void* const* d_in, const int* in_sizes, int n_in,
                              void* d_out, int out_size, void* d_ws, size_t ws_size,
                              hipStream_t stream) {
    const float* x    = (const float*)d_in[0];
    const float* h0   = (const float*)d_in[1];
    const float* W_ih = (const float*)d_in[2];
    const float* b_ih = (const float*)d_in[3];
    const float* W_hh = (const float*)d_in[4];
    const float* b_hh = (const float*)d_in[5];
    const float* W_ho = (const float*)d_in[6];
    const float* b_ho = (const float*)d_in[7];
    rnn_fused<<<B_TOT / BM, 512, 0, stream>>>(x, h0, W_ih, b_ih, W_hh, b_hh,
                                              W_ho, b_ho, (float*)d_out);
}

// Round 17
// 84.684 us; speedup vs baseline: 1.5271x; 1.5271x over previous
//
#include <hip/hip_runtime.h>
#include <hip/hip_bf16.h>

#define B_TOT   4096
#define T_STEPS 256
#define IN_D    28
#define HID     128
#define OUT_D   784
#define BM      16

typedef __bf16 bf16x8 __attribute__((ext_vector_type(8)));
typedef __bf16 bf16x4 __attribute__((ext_vector_type(4)));
typedef float  f32x4  __attribute__((ext_vector_type(4)));
typedef float  f32x2  __attribute__((ext_vector_type(2)));

__device__ __forceinline__ float bf2f(__bf16 b) {
    unsigned short s = __builtin_bit_cast(unsigned short, b);
    unsigned int u = ((unsigned int)s) << 16;
    return __builtin_bit_cast(float, u);
}
__device__ __forceinline__ unsigned short f2bfbits(float f) {
    unsigned int u = __builtin_bit_cast(unsigned int, f);
    u += 0x7fffu + ((u >> 16) & 1u);   // RNE (finite values)
    return (unsigned short)(u >> 16);
}

// Swizzled row layout (verified r7..r15): row stride 256B, byte ^= (row&7)<<4.
__device__ __forceinline__ int hswz(int row, int byteInRow) {
    return row * 256 + (byteInRow ^ ((row & 7) << 4));
}

// Loop barrier: drains LDS only (verified win r15). In-flight x loads survive.
#define BARLDS() asm volatile("s_waitcnt lgkmcnt(0)\n\ts_barrier" ::: "memory")

// r17 = r15 base (best: 86.3us) + x-path amortization: u_t = x_t*W_ih^T + bias
// computed 8 steps at a time into registers u0..u7. Steady-state step shrinks
// from {5 ds_reads, 5 MFMAs} to {4 ds_reads, 4 MFMAs} per wave — the step is
// LDS-wave-instruction-bound (r16 lesson), so fewer instructions = faster.
__global__ __launch_bounds__(512) void rnn_fused(
    const float* __restrict__ x,     // [B,T,IN] f32
    const float* __restrict__ h0,    // [B,HID] f32
    const float* __restrict__ W_ih,  // [HID,IN] f32
    const float* __restrict__ b_ih,  // [HID] f32
    const float* __restrict__ W_hh,  // [HID,HID] f32
    const float* __restrict__ b_hh,  // [HID] f32
    const float* __restrict__ W_ho,  // [OUT_D,HID] f32
    const float* __restrict__ b_ho,  // [OUT_D] f32
    float* __restrict__ out)         // [B*OUT_D] f32, then [B*HID] f32
{
    __shared__ __align__(16) unsigned char Hb[2][BM * 256]; // h (bf16) double buffer
    __shared__ __align__(16) unsigned char Xs[8 * BM * 256];// x ring: 8 swizzled slots

    const int tid  = threadIdx.x;
    const int lane = tid & 63;
    const int wv   = tid >> 6;       // wave 0..7
    const int ln15 = lane & 15;
    const int lg   = lane >> 4;      // k-group 0..3
    const int b0   = blockIdx.x * BM;

    // ---- Weight fragments (f32 -> bf16), register-resident, MFMA *A* operand:
    // A[m = n_out][k], lane: m = nt0 + ln15, k = 8*lg + e.  (verified r7)
    const int nt0 = wv * 16;         // this wave owns hidden cols [nt0, nt0+16)
    bf16x8 bw[4];
    #pragma unroll
    for (int kc = 0; kc < 4; ++kc) {
        const float* p = W_hh + (nt0 + ln15) * HID + kc * 32 + lg * 8;
        bf16x8 v;
        #pragma unroll
        for (int e = 0; e < 8; ++e) v[e] = (__bf16)p[e];
        bw[kc] = v;
    }
    const __bf16 bzero = (__bf16)0.0f;
    bf16x8 bxf;
    {
        int n = nt0 + ln15;
        #pragma unroll
        for (int e = 0; e < 8; ++e) {
            int k = lg * 8 + e;
            bxf[e] = (k < IN_D) ? (__bf16)W_ih[n * IN_D + k] : bzero;  // zero-pad K 28->32
        }
    }
    // bias per lane: D row = n_out = nt0 + 4*lg + r  (4 consecutive)
    f32x4 bias4;
    {
        int n = nt0 + 4 * lg;
        f32x4 bi = *(const f32x4*)(b_ih + n);
        f32x4 bh = *(const f32x4*)(b_hh + n);
        bias4 = bi + bh;
    }

    // ---- stage initial hidden into Hb[0] (f32 -> bf16): first 256 threads
    if (tid < 256) {
        int row = tid >> 4, cg = tid & 15;
        const float* p = h0 + (size_t)(b0 + row) * HID + cg * 8;
        bf16x8 hv;
        #pragma unroll
        for (int e = 0; e < 8; ++e) hv[e] = (__bf16)p[e];
        *(bf16x8*)(&Hb[0][hswz(row, cg * 16)]) = hv;
    }
    // ---- zero the k=28..31 pad (bytes 56..63 of each row) of all 8 ring slots
    if (tid < 256) {
        int slot = tid >> 5, idx = tid & 31, row = idx >> 1, d = idx & 1;
        *(unsigned int*)(&Xs[slot * (BM * 256) + hswz(row, 56 + d * 4)]) = 0u;
    }
    // ---- x staging geometry (verified r7): 224 threads, 16 rows x 14 dword-pairs
    const int xrow = tid / 14, xpair = tid % 14;
    const bool xthr = (tid < 224);
    const float* xbase = x + (size_t)(b0 + xrow) * T_STEPS * IN_D + xpair * 2;
    // ---- pre-stage steps 0..7 into slots 0..7
    if (xthr) {
        #pragma unroll
        for (int s = 0; s < 8; ++s) {
            f32x2 v = *(const f32x2*)(xbase + (size_t)s * IN_D);
            unsigned int pk = ((unsigned int)f2bfbits(v[1]) << 16) | f2bfbits(v[0]);
            *(unsigned int*)(&Xs[s * (BM * 256) + hswz(xrow, xpair * 4)]) = pk;
        }
    }
    f32x2 sx0 = {0.f, 0.f}, sx1 = sx0, sx2 = sx0, sx3 = sx0;
    __syncthreads();

    f32x4 u0, u1, u2, u3, u4, u5, u6, u7;  // u_t for the current 8-block

    // Per 8-block schedule (t = 8-block base, t % 8 == 0 so slot (t+k)&7 == k):
    //   step t+0: PRE8 — 8 ax reads (slots 0..7) + 8 u-MFMAs  [all 8 slots valid]
    //   step t+1: STG_LOAD  x_{t+8..t+11}   (HBM, floats across barriers)
    //   step t+4: STG_WRITE slots 0..3      (read at t+0, free; next read t+8)
    //   step t+5: STG_LOAD  x_{t+12..t+15}
    //   step t+7: STG_WRITE slots 4..7      (BARLDS drains before t+8's PRE8)
    // Steady-state step: 4 h ds_reads, 4 MFMAs (C-in = u_k), 1 b64 h-write.
#define PRE8(T)                                                                 \
        {                                                                       \
            bf16x8 ax0 = *(const bf16x8*)(&Xs[0 * (BM * 256) + hswz(ln15, lg * 16)]); \
            bf16x8 ax1 = *(const bf16x8*)(&Xs[1 * (BM * 256) + hswz(ln15, lg * 16)]); \
            bf16x8 ax2 = *(const bf16x8*)(&Xs[2 * (BM * 256) + hswz(ln15, lg * 16)]); \
            bf16x8 ax3 = *(const bf16x8*)(&Xs[3 * (BM * 256) + hswz(ln15, lg * 16)]); \
            bf16x8 ax4 = *(const bf16x8*)(&Xs[4 * (BM * 256) + hswz(ln15, lg * 16)]); \
            bf16x8 ax5 = *(const bf16x8*)(&Xs[5 * (BM * 256) + hswz(ln15, lg * 16)]); \
            bf16x8 ax6 = *(const bf16x8*)(&Xs[6 * (BM * 256) + hswz(ln15, lg * 16)]); \
            bf16x8 ax7 = *(const bf16x8*)(&Xs[7 * (BM * 256) + hswz(ln15, lg * 16)]); \
            u0 = __builtin_amdgcn_mfma_f32_16x16x32_bf16(bxf, ax0, bias4, 0, 0, 0); \
            u1 = __builtin_amdgcn_mfma_f32_16x16x32_bf16(bxf, ax1, bias4, 0, 0, 0); \
            u2 = __builtin_amdgcn_mfma_f32_16x16x32_bf16(bxf, ax2, bias4, 0, 0, 0); \
            u3 = __builtin_amdgcn_mfma_f32_16x16x32_bf16(bxf, ax3, bias4, 0, 0, 0); \
            u4 = __builtin_amdgcn_mfma_f32_16x16x32_bf16(bxf, ax4, bias4, 0, 0, 0); \
            u5 = __builtin_amdgcn_mfma_f32_16x16x32_bf16(bxf, ax5, bias4, 0, 0, 0); \
            u6 = __builtin_amdgcn_mfma_f32_16x16x32_bf16(bxf, ax6, bias4, 0, 0, 0); \
            u7 = __builtin_amdgcn_mfma_f32_16x16x32_bf16(bxf, ax7, bias4, 0, 0, 0); \
        }

#define STEP(T, U, PRE, STGL, STGW)                                             \
    {                                                                           \
        const int rb = (T) & 1;                                                 \
        PRE                                                                     \
        STGL                                                                    \
        bf16x8 ah0 = *(const bf16x8*)(&Hb[rb][hswz(ln15,   0 + lg * 16)]);      \
        bf16x8 ah1 = *(const bf16x8*)(&Hb[rb][hswz(ln15,  64 + lg * 16)]);      \
        bf16x8 ah2 = *(const bf16x8*)(&Hb[rb][hswz(ln15, 128 + lg * 16)]);      \
        bf16x8 ah3 = *(const bf16x8*)(&Hb[rb][hswz(ln15, 192 + lg * 16)]);      \
        f32x4 zz = {0.f, 0.f, 0.f, 0.f};                                        \
        f32x4 a = __builtin_amdgcn_mfma_f32_16x16x32_bf16(bw[0], ah0, U, 0, 0, 0); \
        f32x4 c = __builtin_amdgcn_mfma_f32_16x16x32_bf16(bw[1], ah1, zz, 0, 0, 0); \
        a = __builtin_amdgcn_mfma_f32_16x16x32_bf16(bw[2], ah2, a, 0, 0, 0);    \
        c = __builtin_amdgcn_mfma_f32_16x16x32_bf16(bw[3], ah3, c, 0, 0, 0);    \
        f32x4 s = a + c;                                                        \
        bf16x4 w;                                                               \
        _Pragma("unroll")                                                       \
        for (int r = 0; r < 4; ++r) {                                           \
            float v = s[r];                                                     \
            w[r] = (__bf16)(v > 0.f ? v : 0.f);                                 \
        }                                                                       \
        *(bf16x4*)(&Hb[rb ^ 1][hswz(ln15, nt0 * 2 + lg * 8)]) = w;              \
        STGW                                                                    \
        BARLDS();                                                               \
    }

#define STG_LOAD(TF)                                                            \
        if (((TF) < T_STEPS) && xthr) {                                         \
            sx0 = *(const f32x2*)(xbase + (size_t)((TF) + 0) * IN_D);           \
            sx1 = *(const f32x2*)(xbase + (size_t)((TF) + 1) * IN_D);           \
            sx2 = *(const f32x2*)(xbase + (size_t)((TF) + 2) * IN_D);           \
            sx3 = *(const f32x2*)(xbase + (size_t)((TF) + 3) * IN_D);           \
        }
#define STG_WRITE(TF)                                                           \
        if (((TF) < T_STEPS) && xthr) {                                         \
            unsigned int p0 = ((unsigned int)f2bfbits(sx0[1]) << 16) | f2bfbits(sx0[0]); \
            unsigned int p1 = ((unsigned int)f2bfbits(sx1[1]) << 16) | f2bfbits(sx1[0]); \
            unsigned int p2 = ((unsigned int)f2bfbits(sx2[1]) << 16) | f2bfbits(sx2[0]); \
            unsigned int p3 = ((unsigned int)f2bfbits(sx3[1]) << 16) | f2bfbits(sx3[0]); \
            *(unsigned int*)(&Xs[(((TF) + 0) & 7) * (BM * 256) + hswz(xrow, xpair * 4)]) = p0; \
            *(unsigned int*)(&Xs[(((TF) + 1) & 7) * (BM * 256) + hswz(xrow, xpair * 4)]) = p1; \
            *(unsigned int*)(&Xs[(((TF) + 2) & 7) * (BM * 256) + hswz(xrow, xpair * 4)]) = p2; \
            *(unsigned int*)(&Xs[(((TF) + 3) & 7) * (BM * 256) + hswz(xrow, xpair * 4)]) = p3; \
        }

    for (int t = 0; t < T_STEPS; t += 8) {
        STEP(t + 0, u0, PRE8(t), , )
        STEP(t + 1, u1, , STG_LOAD(t + 8), )
        STEP(t + 2, u2, , , )
        STEP(t + 3, u3, , , )
        STEP(t + 4, u4, , , STG_WRITE(t + 8))
        STEP(t + 5, u5, , STG_LOAD(t + 12), )
        STEP(t + 6, u6, , , )
        STEP(t + 7, u7, , , STG_WRITE(t + 12))
    }
#undef STEP
#undef PRE8
#undef STG_LOAD
#undef STG_WRITE
    // after t=255 (rb=1) the final h sits in Hb[0]; loop's last BARLDS done

    // ================= epilogue (verified r7) =================
    // h_final -> d_out second segment (f32)
    if (tid < 256) {
        int row = tid >> 4, cg = tid & 15;
        bf16x8 hv = *(const bf16x8*)(&Hb[0][hswz(row, cg * 16)]);
        float* po = out + (size_t)B_TOT * OUT_D + (size_t)(b0 + row) * HID + cg * 8;
        #pragma unroll
        for (int e = 0; e < 8; ++e) po[e] = bf2f(hv[e]);
    }
    // projection (transposed form): D[o][batch], A = W_ho frag, B = h frag.
    bf16x8 af[4];
    #pragma unroll
    for (int kc = 0; kc < 4; ++kc)
        af[kc] = *(const bf16x8*)(&Hb[0][hswz(ln15, kc * 64 + lg * 16)]);

    for (int nt = wv; nt < 49; nt += 8) {
        f32x4 acc = *(const f32x4*)(b_ho + nt * 16 + 4 * lg);
        #pragma unroll
        for (int kc = 0; kc < 4; ++kc) {
            const float* p = W_ho + (nt * 16 + ln15) * HID + kc * 32 + lg * 8;
            bf16x8 bfrag;
            #pragma unroll
            for (int e = 0; e < 8; ++e) bfrag[e] = (__bf16)p[e];
            acc = __builtin_amdgcn_mfma_f32_16x16x32_bf16(bfrag, af[kc], acc, 0, 0, 0);
        }
        // lane holds batch=ln15, o = nt*16 + 4lg + r -> one dwordx4 store
        *(f32x4*)(out + (size_t)(b0 + ln15) * OUT_D + nt * 16 + 4 * lg) = acc;
    }
}

extern "C" void kernel_launch(void* const* d_in, const int* in_sizes, int n_in,
                              void* d_out, int out_size, void* d_ws, size_t ws_size,
                              hipStream_t stream) {
    const float* x    = (const float*)d_in[0];
    const float* h0   = (const float*)d_in[1];
    const float* W_ih = (const float*)d_in[2];
    const float* b_ih = (const float*)d_in[3];
    const float* W_hh = (const float*)d_in[4];
    const float* b_hh = (const float*)d_in[5];
    const float* W_ho = (const float*)d_in[6];
    const float* b_ho = (const float*)d_in[7];
    rnn_fused<<<B_TOT / BM, 512, 0, stream>>>(x, h0, W_ih, b_ih, W_hh, b_hh,
                                              W_ho, b_ho, (float*)d_out);
}